// Round 1
// baseline (160.914 us; speedup 1.0000x reference)
//
#include <hip/hip_runtime.h>
#include <stdint.h>

// ---------------------------------------------------------------------------
// MultiDilatelocalAttention (B=4, H=W=128, C=256, heads=8, K=3, dil={2,3})
//   1) qkv = x @ Wqkv^T            (bf16 MFMA GEMM, M=65536 N=768 K=256)
//   2) dilated 3x3 local attention per (branch, head)   (per-thread, fp32)
//   3) out = xo @ Wproj^T + bproj  (bf16 MFMA GEMM, fp32 out)
// ---------------------------------------------------------------------------

typedef __attribute__((ext_vector_type(8))) short bf16x8;
typedef __attribute__((ext_vector_type(4))) float f32x4;

__device__ __forceinline__ void unpack2(unsigned u, float& lo, float& hi) {
  union { unsigned u; float f; } a, b;
  a.u = u << 16;
  b.u = u & 0xffff0000u;
  lo = a.f; hi = b.f;
}
__device__ __forceinline__ unsigned short f2bf(float f) {
  union { float f; unsigned u; } x; x.f = f;
  unsigned r = x.u + 0x7fffu + ((x.u >> 16) & 1u);   // RNE
  return (unsigned short)(r >> 16);
}
__device__ __forceinline__ unsigned pk2bf(float a, float b) {
  return (unsigned)f2bf(a) | ((unsigned)f2bf(b) << 16);
}

// ------------------------------- fp32 -> bf16 ------------------------------
__global__ __launch_bounds__(256) void cvt_f32_to_bf16(
    const float* __restrict__ src, unsigned short* __restrict__ dst, int n) {
  int i = (blockIdx.x * 256 + threadIdx.x) * 8;
  if (i + 8 <= n) {
    const float4* s = (const float4*)(src + i);
    float4 a = s[0], b = s[1];
    uint4 o;
    o.x = pk2bf(a.x, a.y); o.y = pk2bf(a.z, a.w);
    o.z = pk2bf(b.x, b.y); o.w = pk2bf(b.z, b.w);
    *(uint4*)(dst + i) = o;
  } else {
    for (; i < n; ++i) dst[i] = f2bf(src[i]);
  }
}

// ------------------------- GEMM: C = A @ B^T (bf16) ------------------------
// A: M x K bf16 row-major, B: N x K bf16 row-major.
// 128x128 tile, BK=64, 256 threads (4 waves as 2x2 of 64x64),
// global_load_lds width-16 staging, mfma_f32_16x16x32_bf16 4x4 frags/wave.
template <int OUTF32>
__global__ __launch_bounds__(256) void gemm_bt(
    const unsigned short* __restrict__ A, const unsigned short* __restrict__ B,
    void* __restrict__ Cout, const float* __restrict__ bias,
    int M, int N, int K) {
  __shared__ unsigned short As[128 * 64];
  __shared__ unsigned short Bs[128 * 64];

  const int tid  = threadIdx.x;
  const int lane = tid & 63;
  const int wv   = tid >> 6;
  const int wr   = wv >> 1;   // wave row (0..1)
  const int wc   = wv & 1;    // wave col (0..1)
  const int m0 = blockIdx.x * 128;
  const int n0 = blockIdx.y * 128;

  // staging: per issue `it`, wave wv writes LDS bytes [it*4096 + wv*1024, +1024)
  // lane l covers +l*16 (HW: uniform base + lane*16). Element idx = it*2048+wv*512+l*8
  // -> row = it*32 + wv*8 + l/8, kcol = (l%8)*8.
  const int stg_row = wv * 8 + (lane >> 3);
  const int stg_k   = (lane & 7) * 8;
  const unsigned short* Ag = A + (size_t)(m0 + stg_row) * K + stg_k;
  const unsigned short* Bg = B + (size_t)(n0 + stg_row) * K + stg_k;

  f32x4 acc[4][4];
#pragma unroll
  for (int i = 0; i < 4; ++i)
#pragma unroll
    for (int j = 0; j < 4; ++j) acc[i][j] = (f32x4){0.f, 0.f, 0.f, 0.f};

  const int a_r = lane & 15;         // row within 16x16 fragment
  const int a_k = (lane >> 4) * 8;   // k offset within 32

  const int KT = K >> 6;
  for (int kt = 0; kt < KT; ++kt) {
    const unsigned short* Agt = Ag + kt * 64;
    const unsigned short* Bgt = Bg + kt * 64;
#pragma unroll
    for (int it = 0; it < 4; ++it) {
      __builtin_amdgcn_global_load_lds(
          (const __attribute__((address_space(1))) void*)(Agt + (size_t)it * 32 * K),
          (__attribute__((address_space(3))) void*)&As[it * 2048 + wv * 512],
          16, 0, 0);
      __builtin_amdgcn_global_load_lds(
          (const __attribute__((address_space(1))) void*)(Bgt + (size_t)it * 32 * K),
          (__attribute__((address_space(3))) void*)&Bs[it * 2048 + wv * 512],
          16, 0, 0);
    }
    __syncthreads();   // drains vmcnt before LDS reads
#pragma unroll
    for (int kk = 0; kk < 64; kk += 32) {
      bf16x8 af[4], bf[4];
#pragma unroll
      for (int mi = 0; mi < 4; ++mi)
        af[mi] = *(const bf16x8*)&As[(wr * 64 + mi * 16 + a_r) * 64 + kk + a_k];
#pragma unroll
      for (int ni = 0; ni < 4; ++ni)
        bf[ni] = *(const bf16x8*)&Bs[(wc * 64 + ni * 16 + a_r) * 64 + kk + a_k];
#pragma unroll
      for (int mi = 0; mi < 4; ++mi)
#pragma unroll
        for (int ni = 0; ni < 4; ++ni)
          acc[mi][ni] = __builtin_amdgcn_mfma_f32_16x16x32_bf16(
              af[mi], bf[ni], acc[mi][ni], 0, 0, 0);
    }
    __syncthreads();   // compute done before next-tile staging overwrites LDS
  }

  // epilogue: D[row][col], col = lane&15 (+ni*16), row = (lane>>4)*4 + r (+mi*16)
  const int col0 = n0 + wc * 64 + a_r;
  const int row0 = m0 + wr * 64 + (lane >> 4) * 4;
  if (OUTF32) {
    float* C = (float*)Cout;
#pragma unroll
    for (int ni = 0; ni < 4; ++ni) {
      const int col = col0 + ni * 16;
      const float bv = bias[col];
#pragma unroll
      for (int mi = 0; mi < 4; ++mi)
#pragma unroll
        for (int r = 0; r < 4; ++r)
          C[(size_t)(row0 + mi * 16 + r) * N + col] = acc[mi][ni][r] + bv;
    }
  } else {
    unsigned short* C = (unsigned short*)Cout;
#pragma unroll
    for (int ni = 0; ni < 4; ++ni) {
      const int col = col0 + ni * 16;
#pragma unroll
      for (int mi = 0; mi < 4; ++mi)
#pragma unroll
        for (int r = 0; r < 4; ++r)
          C[(size_t)(row0 + mi * 16 + r) * N + col] = f2bf(acc[mi][ni][r]);
    }
  }
}

// --------------------------- dilated local attention -----------------------
// qkv: [pixel][768] bf16, channel o = t*256 + branch*128 + head*32 + dd
// one thread per (pixel, combo=branch*4+head); 9 zero-padded 3x3 window taps.
__global__ __launch_bounds__(256) void attn_kernel(
    const unsigned short* __restrict__ qkv, unsigned short* __restrict__ xo) {
  const int gid   = blockIdx.x * 256 + threadIdx.x;
  const int combo = gid & 7;
  const int pixel = gid >> 3;
  const int w = pixel & 127;
  const int h = (pixel >> 7) & 127;
  const int b = pixel >> 14;
  const int branch = combo >> 2;
  const int dil = branch ? 3 : 2;           // DILATIONS = (2, 3)
  const int choff = combo * 32;             // = branch*128 + head*32

  const unsigned short* qp = qkv + (size_t)pixel * 768 + choff;
  float q[32];
#pragma unroll
  for (int t = 0; t < 4; ++t) {
    uint4 u = *(const uint4*)(qp + t * 8);
    unpack2(u.x, q[t * 8 + 0], q[t * 8 + 1]);
    unpack2(u.y, q[t * 8 + 2], q[t * 8 + 3]);
    unpack2(u.z, q[t * 8 + 4], q[t * 8 + 5]);
    unpack2(u.w, q[t * 8 + 6], q[t * 8 + 7]);
  }

  // scores: zero-padded unfold => OOB taps have score exactly 0 (not -inf)
  float sc[9];
#pragma unroll
  for (int i = 0; i < 3; ++i) {
#pragma unroll
    for (int j = 0; j < 3; ++j) {
      const int hh = h + (i - 1) * dil;
      const int ww = w + (j - 1) * dil;
      float s = 0.f;
      if ((unsigned)hh < 128u && (unsigned)ww < 128u) {
        const unsigned short* kp =
            qkv + (size_t)((((b << 7) | hh) << 7) | ww) * 768 + 256 + choff;
#pragma unroll
        for (int t = 0; t < 4; ++t) {
          uint4 u = *(const uint4*)(kp + t * 8);
          float a0, a1;
          unpack2(u.x, a0, a1); s += q[t * 8 + 0] * a0 + q[t * 8 + 1] * a1;
          unpack2(u.y, a0, a1); s += q[t * 8 + 2] * a0 + q[t * 8 + 3] * a1;
          unpack2(u.z, a0, a1); s += q[t * 8 + 4] * a0 + q[t * 8 + 5] * a1;
          unpack2(u.w, a0, a1); s += q[t * 8 + 6] * a0 + q[t * 8 + 7] * a1;
        }
      }
      sc[i * 3 + j] = s * 0.17677669529663687f;   // 32^-0.5
    }
  }

  float mx = sc[0];
#pragma unroll
  for (int t = 1; t < 9; ++t) mx = fmaxf(mx, sc[t]);
  float wgt[9], sum = 0.f;
#pragma unroll
  for (int t = 0; t < 9; ++t) { wgt[t] = __expf(sc[t] - mx); sum += wgt[t]; }
  const float inv = 1.f / sum;

  float o[32];
#pragma unroll
  for (int t = 0; t < 32; ++t) o[t] = 0.f;
#pragma unroll
  for (int i = 0; i < 3; ++i) {
#pragma unroll
    for (int j = 0; j < 3; ++j) {
      const int hh = h + (i - 1) * dil;
      const int ww = w + (j - 1) * dil;
      if ((unsigned)hh < 128u && (unsigned)ww < 128u) {
        const float wv = wgt[i * 3 + j] * inv;
        const unsigned short* vp =
            qkv + (size_t)((((b << 7) | hh) << 7) | ww) * 768 + 512 + choff;
#pragma unroll
        for (int t = 0; t < 4; ++t) {
          uint4 u = *(const uint4*)(vp + t * 8);
          float a0, a1;
          unpack2(u.x, a0, a1); o[t * 8 + 0] += wv * a0; o[t * 8 + 1] += wv * a1;
          unpack2(u.y, a0, a1); o[t * 8 + 2] += wv * a0; o[t * 8 + 3] += wv * a1;
          unpack2(u.z, a0, a1); o[t * 8 + 4] += wv * a0; o[t * 8 + 5] += wv * a1;
          unpack2(u.w, a0, a1); o[t * 8 + 6] += wv * a0; o[t * 8 + 7] += wv * a1;
        }
      }
    }
  }

  unsigned short* op = xo + (size_t)pixel * 256 + choff;
#pragma unroll
  for (int t = 0; t < 4; ++t) {
    uint4 u;
    u.x = pk2bf(o[t * 8 + 0], o[t * 8 + 1]);
    u.y = pk2bf(o[t * 8 + 2], o[t * 8 + 3]);
    u.z = pk2bf(o[t * 8 + 4], o[t * 8 + 5]);
    u.w = pk2bf(o[t * 8 + 6], o[t * 8 + 7]);
    *(uint4*)(op + t * 8) = u;
  }
}

// ---------------------------------------------------------------------------
extern "C" void kernel_launch(void* const* d_in, const int* in_sizes, int n_in,
                              void* d_out, int out_size, void* d_ws, size_t ws_size,
                              hipStream_t stream) {
  const float* x     = (const float*)d_in[0];
  const float* Wqkv  = (const float*)d_in[1];
  const float* Wproj = (const float*)d_in[2];
  const float* bproj = (const float*)d_in[3];

  const int M = 4 * 128 * 128;   // 65536 pixels
  const int C = 256;

  // workspace layout (bf16 ushorts): xb | qkv | xo | Wqkv_b | Wproj_b  (~161 MB)
  unsigned short* xb     = (unsigned short*)d_ws;
  unsigned short* qkvb   = xb + (size_t)M * C;
  unsigned short* xob    = qkvb + (size_t)M * 3 * C;
  unsigned short* wqkvb  = xob + (size_t)M * C;
  unsigned short* wprojb = wqkvb + (size_t)3 * C * C;

  cvt_f32_to_bf16<<<(M * C / 8 + 255) / 256, 256, 0, stream>>>(x, xb, M * C);
  cvt_f32_to_bf16<<<(3 * C * C / 8 + 255) / 256, 256, 0, stream>>>(Wqkv, wqkvb, 3 * C * C);
  cvt_f32_to_bf16<<<(C * C / 8 + 255) / 256, 256, 0, stream>>>(Wproj, wprojb, C * C);

  gemm_bt<0><<<dim3(M / 128, (3 * C) / 128), 256, 0, stream>>>(
      xb, wqkvb, (void*)qkvb, nullptr, M, 3 * C, C);

  attn_kernel<<<(M * 8) / 256, 256, 0, stream>>>(qkvb, xob);

  gemm_bt<1><<<dim3(M / 128, C / 128), 256, 0, stream>>>(
      xob, wprojb, d_out, bproj, M, C, C);
}

// Round 4
// 141.272 us; speedup vs baseline: 1.1390x; 1.1390x over previous
//
#include <hip/hip_runtime.h>
#include <stdint.h>

// ---------------------------------------------------------------------------
// MultiDilatelocalAttention (B=4, H=W=128, C=256, heads=8, K=3, dil={2,3})
//   1) qkv = x @ Wqkv^T            (bf16 MFMA GEMM, M=65536 N=768 K=256)
//   2) dilated 3x3 local attention per (branch, head)   (per-thread, fp32)
//   3) out = xo @ Wproj^T + bproj  (bf16 MFMA GEMM, fp32 out)
// GEMM: 128x128 tile, BK=64, KT=4 fully unrolled, double-buffered LDS with
// counted-vmcnt pipeline (T3/T4), XCD-chunked N-major block swizzle (T1),
// LDS-staged coalesced epilogue.
// R4 fix: COMPUTE takes the BUFFER index (0/1/0/1), not the K-tile index —
// COMPUTE(2)/COMPUTE(3) read lds[4..7], past the 64KB array => OOB garbage
// => NaN. (That was the R2/R3 failure; the barrier drain was a red herring,
// though the epilogue does need lgkmcnt(0) before s_barrier, so it stays.)
// ---------------------------------------------------------------------------

typedef __attribute__((ext_vector_type(8))) short bf16x8;
typedef __attribute__((ext_vector_type(4))) float f32x4;

__device__ __forceinline__ void unpack2(unsigned u, float& lo, float& hi) {
  union { unsigned u; float f; } a, b;
  a.u = u << 16;
  b.u = u & 0xffff0000u;
  lo = a.f; hi = b.f;
}
__device__ __forceinline__ unsigned short f2bf(float f) {
  union { float f; unsigned u; } x; x.f = f;
  unsigned r = x.u + 0x7fffu + ((x.u >> 16) & 1u);   // RNE
  return (unsigned short)(r >> 16);
}
__device__ __forceinline__ unsigned pk2bf(float a, float b) {
  return (unsigned)f2bf(a) | ((unsigned)f2bf(b) << 16);
}

// ------------------------------- fp32 -> bf16 ------------------------------
__global__ __launch_bounds__(256) void cvt_f32_to_bf16(
    const float* __restrict__ src, unsigned short* __restrict__ dst, int n) {
  int i = (blockIdx.x * 256 + threadIdx.x) * 8;
  if (i + 8 <= n) {
    const float4* s = (const float4*)(src + i);
    float4 a = s[0], b = s[1];
    uint4 o;
    o.x = pk2bf(a.x, a.y); o.y = pk2bf(a.z, a.w);
    o.z = pk2bf(b.x, b.y); o.w = pk2bf(b.z, b.w);
    *(uint4*)(dst + i) = o;
  } else {
    for (; i < n; ++i) dst[i] = f2bf(src[i]);
  }
}

// ------------------------- GEMM: C = A @ B^T (bf16) ------------------------
// Barrier with LDS-op drain (cross-wave ds_write/ds_read ordering) + sched
// fence (rule #18: keep the scheduler from hoisting past the waitcnt).
#define BARX()                                                \
  do {                                                        \
    asm volatile("s_waitcnt lgkmcnt(0)" ::: "memory");        \
    __builtin_amdgcn_s_barrier();                             \
    __builtin_amdgcn_sched_barrier(0);                        \
  } while (0)
#define WAITVM(n)                                             \
  do {                                                        \
    asm volatile("s_waitcnt vmcnt(" #n ")" ::: "memory");     \
    __builtin_amdgcn_sched_barrier(0);                        \
  } while (0)

template <int OUTF32>
__global__ __launch_bounds__(256) void gemm_bt(
    const unsigned short* __restrict__ A, const unsigned short* __restrict__ B,
    void* __restrict__ Cout, const float* __restrict__ bias,
    int N, int NT) {
  // A0 | B0 | A1 | B1, each 128x64 bf16 = 16 KB. Total 64 KB, reused by epilogue.
  __shared__ __align__(16) unsigned short lds[4][8192];

  const int tid  = threadIdx.x;
  const int lane = tid & 63;
  const int wv   = tid >> 6;
  const int wr   = wv >> 1;   // wave row (0..1)
  const int wc   = wv & 1;    // wave col (0..1)

  // XCD-chunked bijective swizzle (gridDim.x % 8 == 0), N-major tile order:
  // consecutive nid share the same A 128-row panel -> L2 reuse within an XCD.
  const int nwg = gridDim.x;
  const int q8  = nwg >> 3;
  const int nid = (blockIdx.x & 7) * q8 + (blockIdx.x >> 3);
  const int n0  = (nid % NT) * 128;
  const int m0  = (nid / NT) * 128;

  // staging: per issue `it`, wave wv writes LDS bytes [it*4096 + wv*1024, +1024)
  // (HW: uniform base + lane*16). elem = it*2048 + wv*512 + l*8
  //   -> row = it*32 + wv*8 + l/8, kcol = (l%8)*8.   K hardcoded = 256.
  const int stg_row = wv * 8 + (lane >> 3);
  const int stg_k   = (lane & 7) * 8;
  const unsigned short* Ag = A + (size_t)(m0 + stg_row) * 256 + stg_k;
  const unsigned short* Bg = B + (size_t)(n0 + stg_row) * 256 + stg_k;

  f32x4 acc[4][4];
#pragma unroll
  for (int i = 0; i < 4; ++i)
#pragma unroll
    for (int j = 0; j < 4; ++j) acc[i][j] = (f32x4){0.f, 0.f, 0.f, 0.f};

  const int a_r = lane & 15;         // row within 16x16 fragment
  const int a_k = (lane >> 4) * 8;   // k offset within 32

#define STAGE(buf, kt)                                                         \
  do {                                                                         \
    const unsigned short* Asrc = Ag + (kt) * 64;                               \
    const unsigned short* Bsrc = Bg + (kt) * 64;                               \
    _Pragma("unroll")                                                          \
    for (int it = 0; it < 4; ++it) {                                           \
      __builtin_amdgcn_global_load_lds(                                        \
          (const __attribute__((address_space(1))) void*)(Asrc + (size_t)it * 32 * 256), \
          (__attribute__((address_space(3))) void*)&lds[(buf) * 2][it * 2048 + wv * 512], \
          16, 0, 0);                                                           \
      __builtin_amdgcn_global_load_lds(                                        \
          (const __attribute__((address_space(1))) void*)(Bsrc + (size_t)it * 32 * 256), \
          (__attribute__((address_space(3))) void*)&lds[(buf) * 2 + 1][it * 2048 + wv * 512], \
          16, 0, 0);                                                           \
    }                                                                          \
  } while (0)

#define COMPUTE(buf)                                                           \
  do {                                                                         \
    _Pragma("unroll")                                                          \
    for (int kk = 0; kk < 64; kk += 32) {                                      \
      bf16x8 af[4], bfr[4];                                                    \
      _Pragma("unroll")                                                        \
      for (int mi = 0; mi < 4; ++mi)                                           \
        af[mi] = *(const bf16x8*)&lds[(buf) * 2][(wr * 64 + mi * 16 + a_r) * 64 + kk + a_k]; \
      _Pragma("unroll")                                                        \
      for (int ni = 0; ni < 4; ++ni)                                           \
        bfr[ni] = *(const bf16x8*)&lds[(buf) * 2 + 1][(wc * 64 + ni * 16 + a_r) * 64 + kk + a_k]; \
      _Pragma("unroll")                                                        \
      for (int mi = 0; mi < 4; ++mi)                                           \
        _Pragma("unroll")                                                      \
        for (int ni = 0; ni < 4; ++ni)                                         \
          acc[mi][ni] = __builtin_amdgcn_mfma_f32_16x16x32_bf16(               \
              af[mi], bfr[ni], acc[mi][ni], 0, 0, 0);                          \
    }                                                                          \
  } while (0)

  // Depth-2 prefetch pipeline, 8 loads/wave per STAGE; vmcnt counted, never 0
  // until the final tile. K-tiles 0..3 rotate through buffers 0,1,0,1.
  STAGE(0, 0);
  STAGE(1, 1);
  WAITVM(8);  BARX();
  COMPUTE(0);            // kt0 in buf0
  BARX();
  STAGE(0, 2);
  WAITVM(8);  BARX();
  COMPUTE(1);            // kt1 in buf1
  BARX();
  STAGE(1, 3);
  WAITVM(8);  BARX();
  COMPUTE(0);            // kt2 in buf0
  BARX();
  WAITVM(0);  BARX();
  COMPUTE(1);            // kt3 in buf1
  BARX();   // LDS about to be reused by epilogue

  // ------------------- LDS-staged coalesced epilogue -------------------
  const int cl = wc * 64 + a_r;              // local col base
  const int rl = wr * 64 + (lane >> 4) * 4;  // local row base
  if (!OUTF32) {
    // 128 rows x (128+8) bf16, stride 272 B (16B-aligned rows, bank spread)
    unsigned short* eb = &lds[0][0];
#pragma unroll
    for (int ni = 0; ni < 4; ++ni)
#pragma unroll
      for (int mi = 0; mi < 4; ++mi)
#pragma unroll
        for (int r = 0; r < 4; ++r)
          eb[(rl + mi * 16 + r) * 136 + cl + ni * 16] = f2bf(acc[mi][ni][r]);
    BARX();   // lgkmcnt(0) drain inside: publishes ds_writes to all waves
    unsigned short* C = (unsigned short*)Cout;
#pragma unroll
    for (int p = 0; p < 8; ++p) {
      const int idx = p * 256 + tid;
      const int row = idx >> 4;
      const int seg = idx & 15;
      uint4 v = *(const uint4*)&eb[row * 136 + seg * 8];
      *(uint4*)&C[(size_t)(m0 + row) * N + n0 + seg * 8] = v;
    }
  } else {
    // f32: two 64-row halves of (128+4)-f32-stride rows (33792 B each)
    float* ef = (float*)&lds[0][0];
    float* C = (float*)Cout;
    float bv[4];
#pragma unroll
    for (int ni = 0; ni < 4; ++ni) bv[ni] = bias[n0 + wc * 64 + ni * 16 + a_r];
#pragma unroll
    for (int half = 0; half < 2; ++half) {
      if (wr == half) {
        const int rb = (lane >> 4) * 4;   // local row within the half
#pragma unroll
        for (int ni = 0; ni < 4; ++ni)
#pragma unroll
          for (int mi = 0; mi < 4; ++mi)
#pragma unroll
            for (int r = 0; r < 4; ++r)
              ef[(rb + mi * 16 + r) * 132 + wc * 64 + ni * 16 + a_r] =
                  acc[mi][ni][r] + bv[ni];
      }
      BARX();   // lgkmcnt(0) drain inside
#pragma unroll
      for (int p = 0; p < 8; ++p) {
        const int idx = p * 256 + tid;
        const int row = idx >> 5;
        const int seg = idx & 31;
        f32x4 v = *(const f32x4*)&ef[row * 132 + seg * 4];
        *(f32x4*)&C[(size_t)(m0 + half * 64 + row) * N + n0 + seg * 4] = v;
      }
      BARX();
    }
  }
#undef STAGE
#undef COMPUTE
}

// --------------------------- dilated local attention -----------------------
// qkv: [pixel][768] bf16, channel o = t*256 + branch*128 + head*32 + dd
// one thread per (pixel, combo=branch*4+head); 9 zero-padded 3x3 window taps.
__global__ __launch_bounds__(256) void attn_kernel(
    const unsigned short* __restrict__ qkv, unsigned short* __restrict__ xo) {
  // XCD-chunked swizzle: contiguous pixel stripes per XCD for K/V L2 locality
  const int nwg = gridDim.x;
  const int q8  = nwg >> 3;
  const int bid = (blockIdx.x & 7) * q8 + (blockIdx.x >> 3);
  const int gid   = bid * 256 + threadIdx.x;
  const int combo = gid & 7;
  const int pixel = gid >> 3;
  const int w = pixel & 127;
  const int h = (pixel >> 7) & 127;
  const int b = pixel >> 14;
  const int branch = combo >> 2;
  const int dil = branch ? 3 : 2;           // DILATIONS = (2, 3)
  const int choff = combo * 32;             // = branch*128 + head*32

  const unsigned short* qp = qkv + (size_t)pixel * 768 + choff;
  float q[32];
#pragma unroll
  for (int t = 0; t < 4; ++t) {
    uint4 u = *(const uint4*)(qp + t * 8);
    unpack2(u.x, q[t * 8 + 0], q[t * 8 + 1]);
    unpack2(u.y, q[t * 8 + 2], q[t * 8 + 3]);
    unpack2(u.z, q[t * 8 + 4], q[t * 8 + 5]);
    unpack2(u.w, q[t * 8 + 6], q[t * 8 + 7]);
  }

  // scores: zero-padded unfold => OOB taps have score exactly 0 (not -inf)
  float sc[9];
#pragma unroll
  for (int i = 0; i < 3; ++i) {
#pragma unroll
    for (int j = 0; j < 3; ++j) {
      const int hh = h + (i - 1) * dil;
      const int ww = w + (j - 1) * dil;
      float s = 0.f;
      if ((unsigned)hh < 128u && (unsigned)ww < 128u) {
        const unsigned short* kp =
            qkv + (size_t)((((b << 7) | hh) << 7) | ww) * 768 + 256 + choff;
#pragma unroll
        for (int t = 0; t < 4; ++t) {
          uint4 u = *(const uint4*)(kp + t * 8);
          float a0, a1;
          unpack2(u.x, a0, a1); s += q[t * 8 + 0] * a0 + q[t * 8 + 1] * a1;
          unpack2(u.y, a0, a1); s += q[t * 8 + 2] * a0 + q[t * 8 + 3] * a1;
          unpack2(u.z, a0, a1); s += q[t * 8 + 4] * a0 + q[t * 8 + 5] * a1;
          unpack2(u.w, a0, a1); s += q[t * 8 + 6] * a0 + q[t * 8 + 7] * a1;
        }
      }
      sc[i * 3 + j] = s * 0.17677669529663687f;   // 32^-0.5
    }
  }

  float mx = sc[0];
#pragma unroll
  for (int t = 1; t < 9; ++t) mx = fmaxf(mx, sc[t]);
  float wgt[9], sum = 0.f;
#pragma unroll
  for (int t = 0; t < 9; ++t) { wgt[t] = __expf(sc[t] - mx); sum += wgt[t]; }
  const float inv = 1.f / sum;

  float o[32];
#pragma unroll
  for (int t = 0; t < 32; ++t) o[t] = 0.f;
#pragma unroll
  for (int i = 0; i < 3; ++i) {
#pragma unroll
    for (int j = 0; j < 3; ++j) {
      const int hh = h + (i - 1) * dil;
      const int ww = w + (j - 1) * dil;
      if ((unsigned)hh < 128u && (unsigned)ww < 128u) {
        const float wv = wgt[i * 3 + j] * inv;
        const unsigned short* vp =
            qkv + (size_t)((((b << 7) | hh) << 7) | ww) * 768 + 512 + choff;
#pragma unroll
        for (int t = 0; t < 4; ++t) {
          uint4 u = *(const uint4*)(vp + t * 8);
          float a0, a1;
          unpack2(u.x, a0, a1); o[t * 8 + 0] += wv * a0; o[t * 8 + 1] += wv * a1;
          unpack2(u.y, a0, a1); o[t * 8 + 2] += wv * a0; o[t * 8 + 3] += wv * a1;
          unpack2(u.z, a0, a1); o[t * 8 + 4] += wv * a0; o[t * 8 + 5] += wv * a1;
          unpack2(u.w, a0, a1); o[t * 8 + 6] += wv * a0; o[t * 8 + 7] += wv * a1;
        }
      }
    }
  }

  unsigned short* op = xo + (size_t)pixel * 256 + choff;
#pragma unroll
  for (int t = 0; t < 4; ++t) {
    uint4 u;
    u.x = pk2bf(o[t * 8 + 0], o[t * 8 + 1]);
    u.y = pk2bf(o[t * 8 + 2], o[t * 8 + 3]);
    u.z = pk2bf(o[t * 8 + 4], o[t * 8 + 5]);
    u.w = pk2bf(o[t * 8 + 6], o[t * 8 + 7]);
    *(uint4*)(op + t * 8) = u;
  }
}

// ---------------------------------------------------------------------------
extern "C" void kernel_launch(void* const* d_in, const int* in_sizes, int n_in,
                              void* d_out, int out_size, void* d_ws, size_t ws_size,
                              hipStream_t stream) {
  const float* x     = (const float*)d_in[0];
  const float* Wqkv  = (const float*)d_in[1];
  const float* Wproj = (const float*)d_in[2];
  const float* bproj = (const float*)d_in[3];

  const int M = 4 * 128 * 128;   // 65536 pixels
  const int C = 256;

  // workspace layout (bf16 ushorts): xb | qkv | xo | Wqkv_b | Wproj_b  (~161 MB)
  unsigned short* xb     = (unsigned short*)d_ws;
  unsigned short* qkvb   = xb + (size_t)M * C;
  unsigned short* xob    = qkvb + (size_t)M * 3 * C;
  unsigned short* wqkvb  = xob + (size_t)M * C;
  unsigned short* wprojb = wqkvb + (size_t)3 * C * C;

  cvt_f32_to_bf16<<<(M * C / 8 + 255) / 256, 256, 0, stream>>>(x, xb, M * C);
  cvt_f32_to_bf16<<<(3 * C * C / 8 + 255) / 256, 256, 0, stream>>>(Wqkv, wqkvb, 3 * C * C);
  cvt_f32_to_bf16<<<(C * C / 8 + 255) / 256, 256, 0, stream>>>(Wproj, wprojb, C * C);

  gemm_bt<0><<<(M / 128) * (3 * C / 128), 256, 0, stream>>>(
      xb, wqkvb, (void*)qkvb, nullptr, 3 * C, 3 * C / 128);

  attn_kernel<<<(M * 8) / 256, 256, 0, stream>>>(qkvb, xob);

  gemm_bt<1><<<(M / 128) * (C / 128), 256, 0, stream>>>(
      xob, wprojb, d_out, bproj, C, C / 128);
}

// Round 5
// 136.302 us; speedup vs baseline: 1.1806x; 1.0365x over previous
//
#include <hip/hip_runtime.h>
#include <stdint.h>

// ---------------------------------------------------------------------------
// MultiDilatelocalAttention (B=4, H=W=128, C=256, heads=8, K=3, dil={2,3})
//   1) qkv = x @ Wqkv^T            (bf16 MFMA GEMM, M=65536 N=768 K=256)
//   2) dilated 3x3 local attention per (branch, head)   (per-thread, fp32)
//   3) out = xo @ Wproj^T + bproj  (bf16 MFMA GEMM, fp32 out)
// GEMM: 128x128 tile, BK=64, KT=4 fully unrolled, double-buffered LDS with
// counted-vmcnt pipeline (T3/T4), XCD-chunked N-major block swizzle (T1),
// LDS-staged coalesced epilogue.
// R5: T2 XOR-swizzle on the K-loop LDS tiles. The [128][64] bf16 tile has a
// 128 B row stride -> ds_read_b128 col-slices were a 16-way bank conflict
// (9.8M conflict cycles/dispatch = ~16 us/CU). gload_lds writes linearly, so
// per rule #21 we pre-permute the per-lane GLOBAL source (lane l fetches
// granule (l&7)^(l>>3); row&7 == l>>3) and XOR the same involution into the
// read address (granule ^= row&7 == lane&7). Global coalescing unchanged
// (permutation stays inside each row's contiguous 128 B).
// ---------------------------------------------------------------------------

typedef __attribute__((ext_vector_type(8))) short bf16x8;
typedef __attribute__((ext_vector_type(4))) float f32x4;

__device__ __forceinline__ void unpack2(unsigned u, float& lo, float& hi) {
  union { unsigned u; float f; } a, b;
  a.u = u << 16;
  b.u = u & 0xffff0000u;
  lo = a.f; hi = b.f;
}
__device__ __forceinline__ unsigned short f2bf(float f) {
  union { float f; unsigned u; } x; x.f = f;
  unsigned r = x.u + 0x7fffu + ((x.u >> 16) & 1u);   // RNE
  return (unsigned short)(r >> 16);
}
__device__ __forceinline__ unsigned pk2bf(float a, float b) {
  return (unsigned)f2bf(a) | ((unsigned)f2bf(b) << 16);
}

// ------------------------------- fp32 -> bf16 ------------------------------
__global__ __launch_bounds__(256) void cvt_f32_to_bf16(
    const float* __restrict__ src, unsigned short* __restrict__ dst, int n) {
  int i = (blockIdx.x * 256 + threadIdx.x) * 8;
  if (i + 8 <= n) {
    const float4* s = (const float4*)(src + i);
    float4 a = s[0], b = s[1];
    uint4 o;
    o.x = pk2bf(a.x, a.y); o.y = pk2bf(a.z, a.w);
    o.z = pk2bf(b.x, b.y); o.w = pk2bf(b.z, b.w);
    *(uint4*)(dst + i) = o;
  } else {
    for (; i < n; ++i) dst[i] = f2bf(src[i]);
  }
}

// ------------------------- GEMM: C = A @ B^T (bf16) ------------------------
// Barrier with LDS-op drain (cross-wave ds_write/ds_read ordering) + sched
// fence (rule #18: keep the scheduler from hoisting past the waitcnt).
#define BARX()                                                \
  do {                                                        \
    asm volatile("s_waitcnt lgkmcnt(0)" ::: "memory");        \
    __builtin_amdgcn_s_barrier();                             \
    __builtin_amdgcn_sched_barrier(0);                        \
  } while (0)
#define WAITVM(n)                                             \
  do {                                                        \
    asm volatile("s_waitcnt vmcnt(" #n ")" ::: "memory");     \
    __builtin_amdgcn_sched_barrier(0);                        \
  } while (0)

template <int OUTF32>
__global__ __launch_bounds__(256) void gemm_bt(
    const unsigned short* __restrict__ A, const unsigned short* __restrict__ B,
    void* __restrict__ Cout, const float* __restrict__ bias,
    int N, int NT) {
  // A0 | B0 | A1 | B1, each 128x64 bf16 = 16 KB. Total 64 KB, reused by epilogue.
  __shared__ __align__(16) unsigned short lds[4][8192];

  const int tid  = threadIdx.x;
  const int lane = tid & 63;
  const int wv   = tid >> 6;
  const int wr   = wv >> 1;   // wave row (0..1)
  const int wc   = wv & 1;    // wave col (0..1)

  // XCD-chunked bijective swizzle (gridDim.x % 8 == 0), N-major tile order:
  // consecutive nid share the same A 128-row panel -> L2 reuse within an XCD.
  const int nwg = gridDim.x;
  const int q8  = nwg >> 3;
  const int nid = (blockIdx.x & 7) * q8 + (blockIdx.x >> 3);
  const int n0  = (nid % NT) * 128;
  const int m0  = (nid / NT) * 128;

  // staging: per issue `it`, wave wv writes LDS bytes [it*4096 + wv*1024, +1024)
  // (HW: uniform base + lane*16). LDS elem = it*2048 + wv*512 + l*8
  //   -> row = it*32 + wv*8 + l/8 (row&7 == l>>3), granule = l&7.
  // T2: lane fetches global granule (l&7)^(l>>3) so LDS content is XOR-swizzled.
  const int stg_row = wv * 8 + (lane >> 3);
  const int stg_k   = ((lane & 7) ^ (lane >> 3)) * 8;
  const unsigned short* Ag = A + (size_t)(m0 + stg_row) * 256 + stg_k;
  const unsigned short* Bg = B + (size_t)(n0 + stg_row) * 256 + stg_k;

  f32x4 acc[4][4];
#pragma unroll
  for (int i = 0; i < 4; ++i)
#pragma unroll
    for (int j = 0; j < 4; ++j) acc[i][j] = (f32x4){0.f, 0.f, 0.f, 0.f};

  const int a_r = lane & 15;         // row within 16x16 fragment
  // nominal k-granule for this lane at kk: (kk>>3) + (lane>>4); all fragment
  // rows are ==0 mod 8 + a_r, so row&7 == lane&7 for A and B alike.
  const int rsw = lane & 7;

#define STAGE(buf, kt)                                                         \
  do {                                                                         \
    const unsigned short* Asrc = Ag + (kt) * 64;                               \
    const unsigned short* Bsrc = Bg + (kt) * 64;                               \
    _Pragma("unroll")                                                          \
    for (int it = 0; it < 4; ++it) {                                           \
      __builtin_amdgcn_global_load_lds(                                        \
          (const __attribute__((address_space(1))) void*)(Asrc + (size_t)it * 32 * 256), \
          (__attribute__((address_space(3))) void*)&lds[(buf) * 2][it * 2048 + wv * 512], \
          16, 0, 0);                                                           \
      __builtin_amdgcn_global_load_lds(                                        \
          (const __attribute__((address_space(1))) void*)(Bsrc + (size_t)it * 32 * 256), \
          (__attribute__((address_space(3))) void*)&lds[(buf) * 2 + 1][it * 2048 + wv * 512], \
          16, 0, 0);                                                           \
    }                                                                          \
  } while (0)

#define COMPUTE(buf)                                                           \
  do {                                                                         \
    _Pragma("unroll")                                                          \
    for (int kk = 0; kk < 64; kk += 32) {                                      \
      const int gsw = (((kk >> 3) + (lane >> 4)) ^ rsw) * 8;  /* T2 read swz */\
      bf16x8 af[4], bfr[4];                                                    \
      _Pragma("unroll")                                                        \
      for (int mi = 0; mi < 4; ++mi)                                           \
        af[mi] = *(const bf16x8*)&lds[(buf) * 2][(wr * 64 + mi * 16 + a_r) * 64 + gsw]; \
      _Pragma("unroll")                                                        \
      for (int ni = 0; ni < 4; ++ni)                                           \
        bfr[ni] = *(const bf16x8*)&lds[(buf) * 2 + 1][(wc * 64 + ni * 16 + a_r) * 64 + gsw]; \
      _Pragma("unroll")                                                        \
      for (int mi = 0; mi < 4; ++mi)                                           \
        _Pragma("unroll")                                                      \
        for (int ni = 0; ni < 4; ++ni)                                         \
          acc[mi][ni] = __builtin_amdgcn_mfma_f32_16x16x32_bf16(               \
              af[mi], bfr[ni], acc[mi][ni], 0, 0, 0);                          \
    }                                                                          \
  } while (0)

  // Depth-2 prefetch pipeline, 8 loads/wave per STAGE; vmcnt counted, never 0
  // until the final tile. K-tiles 0..3 rotate through buffers 0,1,0,1.
  // Ledger is placement-proof: vmcnt retires in order, so WAITVM(8) always
  // leaves only the newest STAGE outstanding regardless of where the compiler
  // put the (epilogue-only) bias loads.
  STAGE(0, 0);
  STAGE(1, 1);
  WAITVM(8);  BARX();
  COMPUTE(0);            // kt0 in buf0
  BARX();
  STAGE(0, 2);
  WAITVM(8);  BARX();
  COMPUTE(1);            // kt1 in buf1
  BARX();
  STAGE(1, 3);
  WAITVM(8);  BARX();
  COMPUTE(0);            // kt2 in buf0
  BARX();
  WAITVM(0);  BARX();
  COMPUTE(1);            // kt3 in buf1
  BARX();   // LDS about to be reused by epilogue

  // ------------------- LDS-staged coalesced epilogue -------------------
  const int cl = wc * 64 + a_r;              // local col base
  const int rl = wr * 64 + (lane >> 4) * 4;  // local row base
  if (!OUTF32) {
    // 128 rows x (128+8) bf16, stride 272 B (16B-aligned rows, bank spread)
    unsigned short* eb = &lds[0][0];
#pragma unroll
    for (int ni = 0; ni < 4; ++ni)
#pragma unroll
      for (int mi = 0; mi < 4; ++mi)
#pragma unroll
        for (int r = 0; r < 4; ++r)
          eb[(rl + mi * 16 + r) * 136 + cl + ni * 16] = f2bf(acc[mi][ni][r]);
    BARX();   // lgkmcnt(0) drain inside: publishes ds_writes to all waves
    unsigned short* C = (unsigned short*)Cout;
#pragma unroll
    for (int p = 0; p < 8; ++p) {
      const int idx = p * 256 + tid;
      const int row = idx >> 4;
      const int seg = idx & 15;
      uint4 v = *(const uint4*)&eb[row * 136 + seg * 8];
      *(uint4*)&C[(size_t)(m0 + row) * N + n0 + seg * 8] = v;
    }
  } else {
    // f32: two 64-row halves of (128+4)-f32-stride rows (33792 B each)
    float* ef = (float*)&lds[0][0];
    float* C = (float*)Cout;
    float bv[4];
#pragma unroll
    for (int ni = 0; ni < 4; ++ni) bv[ni] = bias[n0 + wc * 64 + ni * 16 + a_r];
#pragma unroll
    for (int half = 0; half < 2; ++half) {
      if (wr == half) {
        const int rb = (lane >> 4) * 4;   // local row within the half
#pragma unroll
        for (int ni = 0; ni < 4; ++ni)
#pragma unroll
          for (int mi = 0; mi < 4; ++mi)
#pragma unroll
            for (int r = 0; r < 4; ++r)
              ef[(rb + mi * 16 + r) * 132 + wc * 64 + ni * 16 + a_r] =
                  acc[mi][ni][r] + bv[ni];
      }
      BARX();   // lgkmcnt(0) drain inside
#pragma unroll
      for (int p = 0; p < 8; ++p) {
        const int idx = p * 256 + tid;
        const int row = idx >> 5;
        const int seg = idx & 31;
        f32x4 v = *(const f32x4*)&ef[row * 132 + seg * 4];
        *(f32x4*)&C[(size_t)(m0 + half * 64 + row) * N + n0 + seg * 4] = v;
      }
      BARX();
    }
  }
#undef STAGE
#undef COMPUTE
}

// --------------------------- dilated local attention -----------------------
// qkv: [pixel][768] bf16, channel o = t*256 + branch*128 + head*32 + dd
// one thread per (pixel, combo=branch*4+head); 9 zero-padded 3x3 window taps.
__global__ __launch_bounds__(256) void attn_kernel(
    const unsigned short* __restrict__ qkv, unsigned short* __restrict__ xo) {
  // XCD-chunked swizzle: contiguous pixel stripes per XCD for K/V L2 locality
  const int nwg = gridDim.x;
  const int q8  = nwg >> 3;
  const int bid = (blockIdx.x & 7) * q8 + (blockIdx.x >> 3);
  const int gid   = bid * 256 + threadIdx.x;
  const int combo = gid & 7;
  const int pixel = gid >> 3;
  const int w = pixel & 127;
  const int h = (pixel >> 7) & 127;
  const int b = pixel >> 14;
  const int branch = combo >> 2;
  const int dil = branch ? 3 : 2;           // DILATIONS = (2, 3)
  const int choff = combo * 32;             // = branch*128 + head*32

  const unsigned short* qp = qkv + (size_t)pixel * 768 + choff;
  float q[32];
#pragma unroll
  for (int t = 0; t < 4; ++t) {
    uint4 u = *(const uint4*)(qp + t * 8);
    unpack2(u.x, q[t * 8 + 0], q[t * 8 + 1]);
    unpack2(u.y, q[t * 8 + 2], q[t * 8 + 3]);
    unpack2(u.z, q[t * 8 + 4], q[t * 8 + 5]);
    unpack2(u.w, q[t * 8 + 6], q[t * 8 + 7]);
  }

  // scores: zero-padded unfold => OOB taps have score exactly 0 (not -inf)
  float sc[9];
#pragma unroll
  for (int i = 0; i < 3; ++i) {
#pragma unroll
    for (int j = 0; j < 3; ++j) {
      const int hh = h + (i - 1) * dil;
      const int ww = w + (j - 1) * dil;
      float s = 0.f;
      if ((unsigned)hh < 128u && (unsigned)ww < 128u) {
        const unsigned short* kp =
            qkv + (size_t)((((b << 7) | hh) << 7) | ww) * 768 + 256 + choff;
#pragma unroll
        for (int t = 0; t < 4; ++t) {
          uint4 u = *(const uint4*)(kp + t * 8);
          float a0, a1;
          unpack2(u.x, a0, a1); s += q[t * 8 + 0] * a0 + q[t * 8 + 1] * a1;
          unpack2(u.y, a0, a1); s += q[t * 8 + 2] * a0 + q[t * 8 + 3] * a1;
          unpack2(u.z, a0, a1); s += q[t * 8 + 4] * a0 + q[t * 8 + 5] * a1;
          unpack2(u.w, a0, a1); s += q[t * 8 + 6] * a0 + q[t * 8 + 7] * a1;
        }
      }
      sc[i * 3 + j] = s * 0.17677669529663687f;   // 32^-0.5
    }
  }

  float mx = sc[0];
#pragma unroll
  for (int t = 1; t < 9; ++t) mx = fmaxf(mx, sc[t]);
  float wgt[9], sum = 0.f;
#pragma unroll
  for (int t = 0; t < 9; ++t) { wgt[t] = __expf(sc[t] - mx); sum += wgt[t]; }
  const float inv = 1.f / sum;

  float o[32];
#pragma unroll
  for (int t = 0; t < 32; ++t) o[t] = 0.f;
#pragma unroll
  for (int i = 0; i < 3; ++i) {
#pragma unroll
    for (int j = 0; j < 3; ++j) {
      const int hh = h + (i - 1) * dil;
      const int ww = w + (j - 1) * dil;
      if ((unsigned)hh < 128u && (unsigned)ww < 128u) {
        const float wv = wgt[i * 3 + j] * inv;
        const unsigned short* vp =
            qkv + (size_t)((((b << 7) | hh) << 7) | ww) * 768 + 512 + choff;
#pragma unroll
        for (int t = 0; t < 4; ++t) {
          uint4 u = *(const uint4*)(vp + t * 8);
          float a0, a1;
          unpack2(u.x, a0, a1); o[t * 8 + 0] += wv * a0; o[t * 8 + 1] += wv * a1;
          unpack2(u.y, a0, a1); o[t * 8 + 2] += wv * a0; o[t * 8 + 3] += wv * a1;
          unpack2(u.z, a0, a1); o[t * 8 + 4] += wv * a0; o[t * 8 + 5] += wv * a1;
          unpack2(u.w, a0, a1); o[t * 8 + 6] += wv * a0; o[t * 8 + 7] += wv * a1;
        }
      }
    }
  }

  unsigned short* op = xo + (size_t)pixel * 256 + choff;
#pragma unroll
  for (int t = 0; t < 4; ++t) {
    uint4 u;
    u.x = pk2bf(o[t * 8 + 0], o[t * 8 + 1]);
    u.y = pk2bf(o[t * 8 + 2], o[t * 8 + 3]);
    u.z = pk2bf(o[t * 8 + 4], o[t * 8 + 5]);
    u.w = pk2bf(o[t * 8 + 6], o[t * 8 + 7]);
    *(uint4*)(op + t * 8) = u;
  }
}

// ---------------------------------------------------------------------------
extern "C" void kernel_launch(void* const* d_in, const int* in_sizes, int n_in,
                              void* d_out, int out_size, void* d_ws, size_t ws_size,
                              hipStream_t stream) {
  const float* x     = (const float*)d_in[0];
  const float* Wqkv  = (const float*)d_in[1];
  const float* Wproj = (const float*)d_in[2];
  const float* bproj = (const float*)d_in[3];

  const int M = 4 * 128 * 128;   // 65536 pixels
  const int C = 256;

  // workspace layout (bf16 ushorts): xb | qkv | xo | Wqkv_b | Wproj_b  (~161 MB)
  unsigned short* xb     = (unsigned short*)d_ws;
  unsigned short* qkvb   = xb + (size_t)M * C;
  unsigned short* xob    = qkvb + (size_t)M * 3 * C;
  unsigned short* wqkvb  = xob + (size_t)M * C;
  unsigned short* wprojb = wqkvb + (size_t)3 * C * C;

  cvt_f32_to_bf16<<<(M * C / 8 + 255) / 256, 256, 0, stream>>>(x, xb, M * C);
  cvt_f32_to_bf16<<<(3 * C * C / 8 + 255) / 256, 256, 0, stream>>>(Wqkv, wqkvb, 3 * C * C);
  cvt_f32_to_bf16<<<(C * C / 8 + 255) / 256, 256, 0, stream>>>(Wproj, wprojb, C * C);

  gemm_bt<0><<<(M / 128) * (3 * C / 128), 256, 0, stream>>>(
      xb, wqkvb, (void*)qkvb, nullptr, 3 * C, 3 * C / 128);

  attn_kernel<<<(M * 8) / 256, 256, 0, stream>>>(qkvb, xob);

  gemm_bt<1><<<(M / 128) * (C / 128), 256, 0, stream>>>(
      xob, wprojb, d_out, bproj, C, C / 128);
}